// Round 21
// baseline (1434.489 us; speedup 1.0000x reference)
//
#include <hip/hip_runtime.h>
#include <hip/hip_bf16.h>
#include <math.h>
#include <stdint.h>

#define BB   512
#define NIN  128
#define DIMD 512
#define QKD  128
#define GSZ  32
#define GRP  4
#define HID  1024
#define HID2 2048
#define NFUSE 2176   // HID2 + QKD
#define ROT  32
#define NLAYER 2
#define EPSF 1e-5f
#define BINS 100

typedef __bf16 bf16x8 __attribute__((ext_vector_type(8)));
typedef float  f32x4  __attribute__((ext_vector_type(4)));
typedef float  f32x16 __attribute__((ext_vector_type(16)));
typedef unsigned short us8 __attribute__((ext_vector_type(8)));

__device__ __forceinline__ unsigned short f2bf(float f) {
    union { float f; uint32_t u; } v; v.f = f;
    return (unsigned short)((v.u + 0x7FFFu + ((v.u >> 16) & 1u)) >> 16);
}
__device__ __forceinline__ float bf2f(unsigned short h) {
    union { uint32_t u; float f; } v; v.u = ((uint32_t)h) << 16;
    return v.f;
}

// ---------------- embedding ----------------
__global__ void k_embed(const int* __restrict__ tokens, const float* __restrict__ emb,
                        const float* __restrict__ pos, float* __restrict__ h) {
    int bn = blockIdx.x;
    int n  = bn % NIN;
    int tok = tokens[bn];
    const float4* e4 = (const float4*)(emb + ((size_t)n * BINS + tok) * DIMD);
    const float4* p4 = (const float4*)(pos + (size_t)n * DIMD);
    float4* h4 = (float4*)(h + (size_t)bn * DIMD);
    int t = threadIdx.x;
    float4 a = e4[t], b = p4[t];
    h4[t] = make_float4(a.x + b.x, a.y + b.y, a.z + b.z, a.w + b.w);
}

// ---------------- fused RMS-norm + half-shift -> nx bf16 ----------------
__global__ void k_nxf(const float* __restrict__ h, unsigned short* __restrict__ nx,
                      const float* __restrict__ ngp) {
    int bn = blockIdx.x; int n = bn % NIN;
    int t = threadIdx.x;   // 0..127
    float4 v = ((const float4*)(h + (size_t)bn * DIMD))[t];
    float sq = v.x * v.x + v.y * v.y + v.z * v.z + v.w * v.w;
    __shared__ float red[2];
    #pragma unroll
    for (int o = 32; o; o >>= 1) sq += __shfl_down(sq, o);
    int lane = t & 63, w = t >> 6;
    if (lane == 0) red[w] = sq;
    __syncthreads();
    float s = red[0] + red[1];
    float nrm = sqrtf(s) * (1.0f / sqrtf((float)DIMD));
    float sc = ngp[0] / fmaxf(nrm, EPSF);
    ushort4 o = make_ushort4(f2bf(v.x * sc), f2bf(v.y * sc), f2bf(v.z * sc), f2bf(v.w * sc));
    if (t < 64) {
        if (n == 0)
            ((ushort4*)(nx + (size_t)bn * DIMD))[t] = make_ushort4(0, 0, 0, 0);
        if (n != NIN - 1)
            ((ushort4*)(nx + (size_t)(bn + 1) * DIMD))[t] = o;
    } else {
        ((ushort4*)(nx + (size_t)bn * DIMD))[t] = o;
    }
}

// ---------------- weight cast+transpose: Wt[n][k] = bf16(W[k][n]) ----------------
__global__ void k_wcast(const float* __restrict__ W, unsigned short* __restrict__ Wt,
                        int K, int N) {
    int idx = blockIdx.x * 256 + threadIdx.x;
    int total = N * (K / 8);
    if (idx >= total) return;
    int kb = idx / N, n = idx % N;
    #pragma unroll
    for (int j = 0; j < 8; ++j)
        Wt[(size_t)n * K + kb * 8 + j] = f2bf(W[(size_t)(kb * 8 + j) * N + n]);
}

#define GLOAD_LDS(gp, lp) __builtin_amdgcn_global_load_lds( \
    (const __attribute__((address_space(1))) uint32_t*)(gp), \
    (__attribute__((address_space(3))) uint32_t*)(lp), 16, 0, 0)

// ---------------- fused Wh+Wqk GEMM: BM=128 x BN=128, BK=32 ----------------
// K-loop: R14-exact 2-deep counted-vmcnt pipeline (best measured).
// Epilogue: reuse the 32KB LDS tile (dead after K-loop) to transpose-stage the
// output so vT and gate stores become 16B full-line runs (kills the scalar 2B /
// strided 8B stores and their L2 write-allocate fetches). qk stores already
// full-line, kept direct.
__global__ __launch_bounds__(256) void k_gemm_f(
        const unsigned short* __restrict__ A,
        const unsigned short* __restrict__ Bt,
        const float* __restrict__ bias0,
        const float* __restrict__ bias1,
        float* __restrict__ Cf,
        unsigned short* __restrict__ vTp,
        unsigned short* __restrict__ gatep,
        int M, int N, int K) {
    __shared__ unsigned short SMEM[16384];   // As[2][4096] | Bs[2][4096] = 32 KB
    const int tid = threadIdx.x;

    int flat = blockIdx.y * gridDim.x + blockIdx.x;
    int nwg  = gridDim.x * gridDim.y;
    int q = nwg >> 3, r = nwg & 7;
    int xcd = flat & 7, idx = flat >> 3;
    int swz = (xcd < r ? xcd * (q + 1) : r * (q + 1) + (xcd - r) * q) + idx;
    const int bxi = swz % gridDim.x, byi = swz / gridDim.x;
    const int bm = byi * 128, bn = bxi * 128;

    const int lane = tid & 63, wave = tid >> 6;
    const int wm = (wave >> 1) * 64, wn = (wave & 1) * 64;
    const int l15 = lane & 15, l4 = lane >> 4;

    f32x4 acc[4][4];
    #pragma unroll
    for (int i = 0; i < 4; ++i)
        #pragma unroll
        for (int j = 0; j < 4; ++j) acc[i][j] = (f32x4){0.f, 0.f, 0.f, 0.f};

    const int rowA = tid >> 2;              // 0..63
    const int colB = (tid & 3) * 16;        // linear byte col
    const char* gA = (const char*)(A  + (size_t)(bm + rowA) * K) + colB;
    const char* gB = (const char*)(Bt + (size_t)(bn + rowA) * K) + colB;
    const size_t stride64 = (size_t)64 * K * 2;

    #define STAGEF(bi, k0) do { \
        const char* sA_ = gA + (size_t)(k0) * 2; \
        const char* sB_ = gB + (size_t)(k0) * 2; \
        GLOAD_LDS(sA_,            &SMEM[(bi) * 4096 + tid * 8]); \
        GLOAD_LDS(sA_ + stride64, &SMEM[(bi) * 4096 + tid * 8 + 2048]); \
        GLOAD_LDS(sB_,            &SMEM[8192 + (bi) * 4096 + tid * 8]); \
        GLOAD_LDS(sB_ + stride64, &SMEM[8192 + (bi) * 4096 + tid * 8 + 2048]); \
    } while (0)

    const int NIT = K / 32;                 // 16
    STAGEF(0, 0);
    STAGEF(1, 32);

    for (int t = 0; t < NIT; ++t) {
        const int cur = t & 1;
        if (t + 1 < NIT) asm volatile("s_waitcnt vmcnt(4)" ::: "memory");
        else             asm volatile("s_waitcnt vmcnt(0)" ::: "memory");
        __builtin_amdgcn_s_barrier();                 // cur buffer visible to all
        __builtin_amdgcn_sched_barrier(0);

        bf16x8 af[4], bfr[4];
        #pragma unroll
        for (int f = 0; f < 4; ++f) {
            af[f]  = *(const bf16x8*)&SMEM[cur * 4096 + (wm + f * 16 + l15) * 32 + l4 * 8];
            bfr[f] = *(const bf16x8*)&SMEM[8192 + cur * 4096 + (wn + f * 16 + l15) * 32 + l4 * 8];
        }
        asm volatile("s_waitcnt lgkmcnt(0)" ::: "memory");
        __builtin_amdgcn_sched_barrier(0);            // rule 18: pin reads complete
        __builtin_amdgcn_s_barrier();                 // all reads of cur done
        __builtin_amdgcn_sched_barrier(0);
        if (t + 2 < NIT) STAGEF(cur, (t + 2) * 32);   // overwrite cur for k=t+2

        #pragma unroll
        for (int i = 0; i < 4; ++i)
            #pragma unroll
            for (int j = 0; j < 4; ++j)
                acc[i][j] = __builtin_amdgcn_mfma_f32_16x16x32_bf16(af[i], bfr[j], acc[i][j], 0, 0, 0);
    }
    #undef STAGEF

    if (bn < HID) {
        // ---- vT block: stage SM[e][n], store e-rows as 16B runs ----
        __syncthreads();
        #pragma unroll
        for (int i = 0; i < 4; ++i) {
            const int n0 = wm + i * 16 + l4 * 4;
            #pragma unroll
            for (int j = 0; j < 4; ++j) {
                const int el = wn + j * 16 + l15;
                float bsv = bias0[bn + el];
                ushort4 o;
                float v0 = acc[i][j][0] + bsv; o.x = f2bf(v0 / (1.0f + __expf(-v0)));
                float v1 = acc[i][j][1] + bsv; o.y = f2bf(v1 / (1.0f + __expf(-v1)));
                float v2 = acc[i][j][2] + bsv; o.z = f2bf(v2 / (1.0f + __expf(-v2)));
                float v3 = acc[i][j][3] + bsv; o.w = f2bf(v3 / (1.0f + __expf(-v3)));
                *(ushort4*)&SMEM[el * 128 + n0] = o;
            }
        }
        __syncthreads();
        const int e  = tid >> 1;
        const int nb = (tid & 1) * 64;
        unsigned short* dst = vTp + ((size_t)byi * HID + bn + e) * NIN + nb;
        #pragma unroll
        for (int k = 0; k < 8; ++k)
            *(us8*)&dst[k * 8] = *(const us8*)&SMEM[e * 128 + nb + k * 8];
    } else if (bn < 2 * HID) {
        // ---- gate block: stage SM[n][e], store n-rows as 16B runs ----
        __syncthreads();
        #pragma unroll
        for (int i = 0; i < 4; ++i) {
            const int n0 = wm + i * 16 + l4 * 4;
            #pragma unroll
            for (int j = 0; j < 4; ++j) {
                const int el = wn + j * 16 + l15;
                float bsv = bias0[bn + el];
                #pragma unroll
                for (int rr = 0; rr < 4; ++rr) {
                    float v = acc[i][j][rr] + bsv;
                    SMEM[(n0 + rr) * 128 + el] = f2bf(v / (1.0f + __expf(-v)));
                }
            }
        }
        __syncthreads();
        const int n  = tid >> 1;
        const int eb = (tid & 1) * 64;
        unsigned short* dst = gatep + (size_t)(bm + n) * HID + (bn - HID) + eb;
        #pragma unroll
        for (int k = 0; k < 8; ++k)
            *(us8*)&dst[k * 8] = *(const us8*)&SMEM[n * 128 + eb + k * 8];
    } else {
        // ---- qk block: stores are already full-line; direct ----
        #pragma unroll
        for (int i = 0; i < 4; ++i) {
            const int n0 = wm + i * 16 + l4 * 4;
            #pragma unroll
            for (int j = 0; j < 4; ++j) {
                const int col = wn + j * 16 + l15;
                float bsv = bias1[col];
                #pragma unroll
                for (int rr = 0; rr < 4; ++rr) {
                    float v = acc[i][j][rr] + bsv;
                    Cf[(size_t)(bm + n0 + rr) * QKD + col] = v / (1.0f + __expf(-v));
                }
            }
        }
    }
}

// ---------------- Wout GEMM: BM=256 x BN=128, BK=32, dbuf prefetch (R14-exact) ----------------
__global__ __launch_bounds__(256, 2) void k_gemm_o(
        const unsigned short* __restrict__ A,
        const unsigned short* __restrict__ Bt,
        const float* __restrict__ bias0,
        const float* __restrict__ resid,
        float* __restrict__ Cf,
        int M, int N, int K) {
    __shared__ unsigned short As[2][256 * 32];
    __shared__ unsigned short Bs[2][128 * 32];
    const int tid = threadIdx.x;

    int flat = blockIdx.y * gridDim.x + blockIdx.x;
    int nwg  = gridDim.x * gridDim.y;
    int q = nwg >> 3, r = nwg & 7;
    int xcd = flat & 7, idx = flat >> 3;
    int swz = (xcd < r ? xcd * (q + 1) : r * (q + 1) + (xcd - r) * q) + idx;
    const int bxi = swz % gridDim.x, byi = swz / gridDim.x;
    const int bm = byi * 256, bn = bxi * 128;

    const int lane = tid & 63, wave = tid >> 6;   // wave w: rows [64w, 64w+64)
    const int l15 = lane & 15, l4 = lane >> 4;

    f32x4 acc[4][8];
    #pragma unroll
    for (int i = 0; i < 4; ++i)
        #pragma unroll
        for (int j = 0; j < 8; ++j) acc[i][j] = (f32x4){0.f, 0.f, 0.f, 0.f};

    const int rowA = tid >> 2;
    const int colO = (tid & 3) * 16;
    const int colS = colO ^ ((rowA & 3) << 4);
    const char* gA = (const char*)(A  + (size_t)(bm + rowA) * K) + colS;
    const char* gB = (const char*)(Bt + (size_t)(bn + rowA) * K) + colS;
    const size_t stride64 = (size_t)64 * K * 2;
    unsigned short* dA0 = &As[0][tid * 8];
    unsigned short* dA1 = &As[1][tid * 8];
    unsigned short* dB0 = &Bs[0][tid * 8];
    unsigned short* dB1 = &Bs[1][tid * 8];

    #define STAGE2(dA, dB, k0) do { \
        const char* sA_ = gA + (size_t)(k0) * 2; \
        const char* sB_ = gB + (size_t)(k0) * 2; \
        GLOAD_LDS(sA_,                 (dA)); \
        GLOAD_LDS(sA_ +     stride64,  (dA) + 2048); \
        GLOAD_LDS(sA_ + 2 * stride64,  (dA) + 4096); \
        GLOAD_LDS(sA_ + 3 * stride64,  (dA) + 6144); \
        GLOAD_LDS(sB_,                 (dB)); \
        GLOAD_LDS(sB_ +     stride64,  (dB) + 2048); \
    } while (0)

    STAGE2(dA0, dB0, 0);
    asm volatile("s_waitcnt vmcnt(0)" ::: "memory");
    __syncthreads();

    const int NIT = K / 32;
    int bufc = 0;
    for (int it = 0; it < NIT; ++it) {
        if (it + 1 < NIT) {
            if (bufc == 0) STAGE2(dA1, dB1, (it + 1) * 32);
            else           STAGE2(dA0, dB0, (it + 1) * 32);
        }
        const unsigned short* Ab = As[bufc];
        const unsigned short* Bb = Bs[bufc];
        bf16x8 af[4], bfr[8];
        #pragma unroll
        for (int f = 0; f < 4; ++f) {
            int rA = wave * 64 + f * 16 + l15;
            af[f] = *(const bf16x8*)&Ab[rA * 32 + ((l4 ^ (rA & 3)) << 3)];
        }
        #pragma unroll
        for (int c = 0; c < 8; ++c) {
            int rB = c * 16 + l15;
            bfr[c] = *(const bf16x8*)&Bb[rB * 32 + ((l4 ^ (rB & 3)) << 3)];
        }
        #pragma unroll
        for (int f = 0; f < 4; ++f)
            #pragma unroll
            for (int c = 0; c < 8; ++c)
                acc[f][c] = __builtin_amdgcn_mfma_f32_16x16x32_bf16(af[f], bfr[c], acc[f][c], 0, 0, 0);
        asm volatile("s_waitcnt vmcnt(0)" ::: "memory");
        __syncthreads();
        bufc ^= 1;
    }
    #undef STAGE2

    #pragma unroll
    for (int f = 0; f < 4; ++f) {
        const int n0 = wave * 64 + f * 16 + l4 * 4;
        #pragma unroll
        for (int c = 0; c < 8; ++c) {
            const int col = bn + c * 16 + l15;
            float bsv = bias0[col];
            #pragma unroll
            for (int rr = 0; rr < 4; ++rr) {
                size_t row = bm + n0 + rr;
                Cf[row * N + col] = acc[f][c][rr] + bsv + resid[row * N + col];
            }
        }
    }
}

// ---------------- rotary cos/sin tables ----------------
__global__ void k_cossin(float* __restrict__ cosb, float* __restrict__ sinb) {
    int idx = blockIdx.x * 256 + threadIdx.x;
    if (idx >= NIN * 16) return;
    int n = idx / 16, i = idx % 16;
    double inv = pow(10000.0, -(double)(2 * i) / (double)ROT);
    double f = (double)n * inv;
    cosb[idx] = (float)cos(f);
    sinb[idx] = (float)sin(f);
}

// ---------------- qs = qk*gamma+beta (4 heads) + rotary, bf16 out ----------------
__global__ void k_rot(const float* __restrict__ qk, const float* __restrict__ gm,
                      const float* __restrict__ bt, const float* __restrict__ cosb,
                      const float* __restrict__ sinb, unsigned short* __restrict__ q4) {
    int bn = blockIdx.x; int n = bn % NIN;
    int d = threadIdx.x;   // 128
    float x = qk[(size_t)bn * QKD + d];
    float xp0 = 0.f;
    int dp = d ^ 1;
    if (d < ROT) xp0 = qk[(size_t)bn * QKD + dp];
    #pragma unroll
    for (int c = 0; c < 4; ++c) {
        float val = x * gm[c * QKD + d] + bt[c * QKD + d];
        float outv;
        if (d < ROT) {
            int i = d >> 1;
            float cs = cosb[n * 16 + i], sn = sinb[n * 16 + i];
            float xp = xp0 * gm[c * QKD + dp] + bt[c * QKD + dp];
            outv = ((d & 1) == 0) ? (val * cs - xp * sn) : (val * cs + xp * sn);
        } else outv = val;
        q4[((size_t)bn * 4 + c) * QKD + d] = f2bf(outv);
    }
}

// ---------------- MFMA fused attention ----------------
__global__ __launch_bounds__(256) void k_attn2(
        const unsigned short* __restrict__ q4,
        const unsigned short* __restrict__ gatep,
        const unsigned short* __restrict__ vT,
        const float* __restrict__ rp,
        unsigned short* __restrict__ attn_out) {
    int et = blockIdx.x, b = blockIdx.y;
    int tid = threadIdx.x, wave = tid >> 6, lane = tid & 63;
    int l31 = lane & 31, lhi = lane >> 5;

    __shared__ unsigned short S[32][136];
    __shared__ float rps_d[32];
    if (tid < 32) {
        int d = tid, bucket;
        if (d < 16) bucket = d;
        else {
            bucket = 16 + (int)(logf((float)d * (1.0f / 16.0f)) * (16.0f / logf(8.0f)));
            if (bucket > 31) bucket = 31;
        }
        rps_d[tid] = rp[bucket] * sqrtf((float)QKD);
    }
    __syncthreads();

    size_t bbase = (size_t)b * NIN;
    int e0 = et * 256 + wave * 64;
    const unsigned short* vbase = vT + (size_t)b * HID * NIN;

    for (int g = 0; g < GRP; ++g) {
        if (wave <= g) {
            int gp = wave;
            bool quad = (gp == g);
            const unsigned short* Qb = q4 + ((bbase + g  * 32 + l31) * 4 + (quad ? 0 : 1)) * QKD;
            const unsigned short* Kb = q4 + ((bbase + gp * 32 + l31) * 4 + (quad ? 2 : 3)) * QKD;
            f32x16 sa = {};
            #pragma unroll
            for (int kk = 0; kk < 8; ++kk) {
                bf16x8 aq = *(const bf16x8*)(Qb + kk * 16 + lhi * 8);
                bf16x8 bk = *(const bf16x8*)(Kb + kk * 16 + lhi * 8);
                sa = __builtin_amdgcn_mfma_f32_32x32x16_bf16(aq, bk, sa, 0, 0, 0);
            }
            int j = l31;
            #pragma unroll
            for (int r = 0; r < 16; ++r) {
                int i = (r & 3) + 8 * (r >> 2) + 4 * lhi;
                float s = sa[r] * (1.0f / GSZ);
                if (quad) {
                    if (j > i) s = 0.f;
                    else {
                        s += rps_d[i - j];
                        s = fmaxf(s, 0.f);
                        s = s * s;
                    }
                }
                S[i][gp * 32 + j] = f2bf(s);
            }
        }
        __syncthreads();

        f32x16 o0 = {}, o1 = {};
        int KT = 2 * (g + 1);
        for (int kk = 0; kk < KT; ++kk) {
            int k0 = kk * 16 + lhi * 8;
            bf16x8 af = *(const bf16x8*)&S[l31][k0];
            bf16x8 b0 = *(const bf16x8*)(vbase + (size_t)(e0 + l31) * NIN + k0);
            bf16x8 b1 = *(const bf16x8*)(vbase + (size_t)(e0 + 32 + l31) * NIN + k0);
            o0 = __builtin_amdgcn_mfma_f32_32x32x16_bf16(af, b0, o0, 0, 0, 0);
            o1 = __builtin_amdgcn_mfma_f32_32x32x16_bf16(af, b1, o1, 0, 0, 0);
        }
        __syncthreads();

        int ea = e0 + l31, eb = e0 + 32 + l31;
        #pragma unroll
        for (int r = 0; r < 16; ++r) {
            int i = (r & 3) + 8 * (r >> 2) + 4 * lhi;
            size_t row = bbase + g * 32 + i;
            float ga = bf2f(gatep[row * HID + ea]);
            float gb = bf2f(gatep[row * HID + eb]);
            attn_out[row * HID + ea] = f2bf(ga * o0[r]);
            attn_out[row * HID + eb] = f2bf(gb * o1[r]);
        }
    }
}

// ---------------- final LayerNorm ----------------
__global__ void k_ln(const float* __restrict__ h, const float* __restrict__ lng,
                     const float* __restrict__ lnb, float* __restrict__ out) {
    int bn = blockIdx.x;
    int t = threadIdx.x;
    const float4* r4 = (const float4*)(h + (size_t)bn * DIMD);
    float4 v = r4[t];
    float s  = v.x + v.y + v.z + v.w;
    float sq = v.x * v.x + v.y * v.y + v.z * v.z + v.w * v.w;
    __shared__ float red[4];
    #pragma unroll
    for (int o = 32; o; o >>= 1) { s += __shfl_down(s, o); sq += __shfl_down(sq, o); }
    int lane = t & 63, w = t >> 6;
    if (lane == 0) { red[w] = s; red[2 + w] = sq; }
    __syncthreads();
    float mu  = (red[0] + red[1]) * (1.0f / DIMD);
    float var = (red[2] + red[3]) * (1.0f / DIMD) - mu * mu;
    float rstd = 1.0f / sqrtf(var + EPSF);
    float4 gg = ((const float4*)lng)[t];
    float4 bb = ((const float4*)lnb)[t];
    float4 o;
    o.x = (v.x - mu) * rstd * gg.x + bb.x;
    o.y = (v.y - mu) * rstd * gg.y + bb.y;
    o.z = (v.z - mu) * rstd * gg.z + bb.z;
    o.w = (v.w - mu) * rstd * gg.w + bb.w;
    ((float4*)(out + (size_t)bn * DIMD))[t] = o;
}

extern "C" void kernel_launch(void* const* d_in, const int* in_sizes, int n_in,
                              void* d_out, int out_size, void* d_ws, size_t ws_size,
                              hipStream_t stream) {
    const int*   tokens = (const int*)d_in[0];
    const float* emb    = (const float*)d_in[1];
    const float* pos    = (const float*)d_in[2];
    const float* norm_g = (const float*)d_in[3];
    const float* Wh     = (const float*)d_in[4];
    const float* bh     = (const float*)d_in[5];
    const float* Wqk    = (const float*)d_in[6];
    const float* bqk    = (const float*)d_in[7];
    const float* gamma  = (const float*)d_in[8];
    const float* beta   = (const float*)d_in[9];
    const float* rp     = (const float*)d_in[10];
    const float* Wout   = (const float*)d_in[11];
    const float* bout   = (const float*)d_in[12];
    const float* lng    = (const float*)d_in[13];
    const float* lnb    = (const float*)d_in[14];

    float* h  = (float*)d_out;
    float* ws = (float*)d_ws;

    // ---- fixed allocations ----
    size_t off = 0;
    float* cosb  = ws + off; off += NIN * 16;
    float* sinb  = ws + off; off += NIN * 16;
    unsigned short* whqkT = (unsigned short*)(ws + off); off += (size_t)NLAYER * NFUSE * DIMD / 2;
    unsigned short* woutT = (unsigned short*)(ws + off); off += (size_t)NLAYER * DIMD * HID / 2;
    off = (off + 63) & ~(size_t)63;
    const size_t fixedFloats = off;

    // ---- size batch chunk (keep CB >= 2 so M % 256 == 0 for k_gemm_o) ----
    const size_t wsFloats = ws_size / sizeof(float);
    const size_t perBatch = (size_t)NIN * (DIMD / 2 + HID / 2 + HID / 2 + QKD + DIMD / 2 + HID / 2);
    int CB = BB;
    while (CB > 2 && fixedFloats + (size_t)CB * perBatch + 64 > wsFloats) CB >>= 1;

    unsigned short* nx    = (unsigned short*)(ws + off); off += (size_t)CB * NIN * DIMD / 2;
    unsigned short* vT    = (unsigned short*)(ws + off); off += (size_t)CB * HID * NIN / 2;
    unsigned short* gateB = (unsigned short*)(ws + off); off += (size_t)CB * NIN * HID / 2;
    float*          qk    = ws + off;                    off += (size_t)CB * NIN * QKD;
    unsigned short* q4    = (unsigned short*)(ws + off); off += (size_t)CB * NIN * DIMD / 2;
    unsigned short* attnB = (unsigned short*)(ws + off); off += (size_t)CB * NIN * HID / 2;

    const int BN_ = BB * NIN;

    k_cossin<<<8, 256, 0, stream>>>(cosb, sinb);
    k_embed<<<BN_, 128, 0, stream>>>(tokens, emb, pos, h);

    for (int l = 0; l < NLAYER; ++l) {
        unsigned short* whqkT_l = whqkT + (size_t)l * NFUSE * DIMD;
        k_wcast<<<(HID2 * DIMD / 8 + 255) / 256, 256, 0, stream>>>(
            Wh + (size_t)l * DIMD * HID2,  whqkT_l, DIMD, HID2);
        k_wcast<<<(QKD * DIMD / 8 + 255) / 256, 256, 0, stream>>>(
            Wqk + (size_t)l * DIMD * QKD,  whqkT_l + (size_t)HID2 * DIMD, DIMD, QKD);
        k_wcast<<<(DIMD * HID / 8 + 255) / 256, 256, 0, stream>>>(
            Wout + (size_t)l * HID * DIMD, woutT + (size_t)l * DIMD * HID, HID, DIMD);
    }

    for (int l = 0; l < NLAYER; ++l) {
        const float* bh_l  = bh   + (size_t)l * HID2;
        const float* bqk_l = bqk  + (size_t)l * QKD;
        const float* gm_l  = gamma+ (size_t)l * 4 * QKD;
        const float* bt_l  = beta + (size_t)l * 4 * QKD;
        const float* rp_l  = rp   + (size_t)l * 32;
        const float* bo_l  = bout + (size_t)l * DIMD;
        const unsigned short* whqkT_l = whqkT + (size_t)l * NFUSE * DIMD;
        const unsigned short* woutT_l = woutT + (size_t)l * DIMD * HID;

        for (int c0 = 0; c0 < BB; c0 += CB) {
            const int rowsC = CB * NIN;
            float* h_c = h + (size_t)c0 * NIN * DIMD;

            k_nxf<<<rowsC, 128, 0, stream>>>(h_c, nx, norm_g + l);

            dim3 g1(NFUSE / 128, rowsC / 128);
            k_gemm_f<<<g1, 256, 0, stream>>>(nx, whqkT_l, bh_l, bqk_l,
                                             qk, vT, gateB, rowsC, NFUSE, DIMD);

            k_rot<<<rowsC, 128, 0, stream>>>(qk, gm_l, bt_l, cosb, sinb, q4);

            dim3 ga(HID / 256, CB);
            k_attn2<<<ga, 256, 0, stream>>>(q4, gateB, vT, rp_l, attnB);

            dim3 g3(DIMD / 128, rowsC / 256);
            k_gemm_o<<<g3, 256, 0, stream>>>(attnB, woutT_l, bo_l, h_c, h_c,
                                             rowsC, DIMD, HID);
        }
    }

    k_ln<<<BN_, 128, 0, stream>>>(h, lng, lnb, (float*)d_out);
}

// Round 22
// 1345.831 us; speedup vs baseline: 1.0659x; 1.0659x over previous
//
#include <hip/hip_runtime.h>
#include <hip/hip_bf16.h>
#include <math.h>
#include <stdint.h>

#define BB   512
#define NIN  128
#define DIMD 512
#define QKD  128
#define GSZ  32
#define GRP  4
#define HID  1024
#define HID2 2048
#define NFUSE 2176   // HID2 + QKD
#define ROT  32
#define NLAYER 2
#define EPSF 1e-5f
#define BINS 100

typedef __bf16 bf16x8 __attribute__((ext_vector_type(8)));
typedef float  f32x4  __attribute__((ext_vector_type(4)));
typedef float  f32x16 __attribute__((ext_vector_type(16)));

__device__ __forceinline__ unsigned short f2bf(float f) {
    union { float f; uint32_t u; } v; v.f = f;
    return (unsigned short)((v.u + 0x7FFFu + ((v.u >> 16) & 1u)) >> 16);
}
__device__ __forceinline__ float bf2f(unsigned short h) {
    union { uint32_t u; float f; } v; v.u = ((uint32_t)h) << 16;
    return v.f;
}

// ---------------- embedding ----------------
__global__ void k_embed(const int* __restrict__ tokens, const float* __restrict__ emb,
                        const float* __restrict__ pos, float* __restrict__ h) {
    int bn = blockIdx.x;
    int n  = bn % NIN;
    int tok = tokens[bn];
    const float4* e4 = (const float4*)(emb + ((size_t)n * BINS + tok) * DIMD);
    const float4* p4 = (const float4*)(pos + (size_t)n * DIMD);
    float4* h4 = (float4*)(h + (size_t)bn * DIMD);
    int t = threadIdx.x;
    float4 a = e4[t], b = p4[t];
    h4[t] = make_float4(a.x + b.x, a.y + b.y, a.z + b.z, a.w + b.w);
}

// ---------------- fused RMS-norm + half-shift -> nx bf16 ----------------
__global__ void k_nxf(const float* __restrict__ h, unsigned short* __restrict__ nx,
                      const float* __restrict__ ngp) {
    int bn = blockIdx.x; int n = bn % NIN;
    int t = threadIdx.x;   // 0..127
    float4 v = ((const float4*)(h + (size_t)bn * DIMD))[t];
    float sq = v.x * v.x + v.y * v.y + v.z * v.z + v.w * v.w;
    __shared__ float red[2];
    #pragma unroll
    for (int o = 32; o; o >>= 1) sq += __shfl_down(sq, o);
    int lane = t & 63, w = t >> 6;
    if (lane == 0) red[w] = sq;
    __syncthreads();
    float s = red[0] + red[1];
    float nrm = sqrtf(s) * (1.0f / sqrtf((float)DIMD));
    float sc = ngp[0] / fmaxf(nrm, EPSF);
    ushort4 o = make_ushort4(f2bf(v.x * sc), f2bf(v.y * sc), f2bf(v.z * sc), f2bf(v.w * sc));
    if (t < 64) {
        if (n == 0)
            ((ushort4*)(nx + (size_t)bn * DIMD))[t] = make_ushort4(0, 0, 0, 0);
        if (n != NIN - 1)
            ((ushort4*)(nx + (size_t)(bn + 1) * DIMD))[t] = o;
    } else {
        ((ushort4*)(nx + (size_t)bn * DIMD))[t] = o;
    }
}

// ---------------- weight cast+transpose: Wt[n][k] = bf16(W[k][n]) ----------------
__global__ void k_wcast(const float* __restrict__ W, unsigned short* __restrict__ Wt,
                        int K, int N) {
    int idx = blockIdx.x * 256 + threadIdx.x;
    int total = N * (K / 8);
    if (idx >= total) return;
    int kb = idx / N, n = idx % N;
    #pragma unroll
    for (int j = 0; j < 8; ++j)
        Wt[(size_t)n * K + kb * 8 + j] = f2bf(W[(size_t)(kb * 8 + j) * N + n]);
}

#define GLOAD_LDS(gp, lp) __builtin_amdgcn_global_load_lds( \
    (const __attribute__((address_space(1))) uint32_t*)(gp), \
    (__attribute__((address_space(3))) uint32_t*)(lp), 16, 0, 0)

// ---------------- fused Wh+Wqk GEMM: BM=128 x BN=128, BK=32 ----------------
// R14-exact 2-deep counted-vmcnt pipeline (measured best: 164us/dispatch).
__global__ __launch_bounds__(256) void k_gemm_f(
        const unsigned short* __restrict__ A,
        const unsigned short* __restrict__ Bt,
        const float* __restrict__ bias0,
        const float* __restrict__ bias1,
        float* __restrict__ Cf,
        unsigned short* __restrict__ vTp,
        unsigned short* __restrict__ gatep,
        int M, int N, int K) {
    __shared__ unsigned short As[2][128 * 32];   // 2 x 8 KB
    __shared__ unsigned short Bs[2][128 * 32];   // 2 x 8 KB
    const int tid = threadIdx.x;

    int flat = blockIdx.y * gridDim.x + blockIdx.x;
    int nwg  = gridDim.x * gridDim.y;
    int q = nwg >> 3, r = nwg & 7;
    int xcd = flat & 7, idx = flat >> 3;
    int swz = (xcd < r ? xcd * (q + 1) : r * (q + 1) + (xcd - r) * q) + idx;
    const int bxi = swz % gridDim.x, byi = swz / gridDim.x;
    const int bm = byi * 128, bn = bxi * 128;

    const int lane = tid & 63, wave = tid >> 6;
    const int wm = (wave >> 1) * 64, wn = (wave & 1) * 64;
    const int l15 = lane & 15, l4 = lane >> 4;

    f32x4 acc[4][4];
    #pragma unroll
    for (int i = 0; i < 4; ++i)
        #pragma unroll
        for (int j = 0; j < 4; ++j) acc[i][j] = (f32x4){0.f, 0.f, 0.f, 0.f};

    const int rowA = tid >> 2;              // 0..63
    const int colB = (tid & 3) * 16;        // linear byte col
    const char* gA = (const char*)(A  + (size_t)(bm + rowA) * K) + colB;
    const char* gB = (const char*)(Bt + (size_t)(bn + rowA) * K) + colB;
    const size_t stride64 = (size_t)64 * K * 2;

    #define STAGEF(bi, k0) do { \
        const char* sA_ = gA + (size_t)(k0) * 2; \
        const char* sB_ = gB + (size_t)(k0) * 2; \
        GLOAD_LDS(sA_,            &As[bi][tid * 8]); \
        GLOAD_LDS(sA_ + stride64, &As[bi][tid * 8 + 2048]); \
        GLOAD_LDS(sB_,            &Bs[bi][tid * 8]); \
        GLOAD_LDS(sB_ + stride64, &Bs[bi][tid * 8 + 2048]); \
    } while (0)

    const int NIT = K / 32;                 // 16
    STAGEF(0, 0);
    STAGEF(1, 32);

    for (int t = 0; t < NIT; ++t) {
        const int cur = t & 1;
        if (t + 1 < NIT) asm volatile("s_waitcnt vmcnt(4)" ::: "memory");
        else             asm volatile("s_waitcnt vmcnt(0)" ::: "memory");
        __builtin_amdgcn_s_barrier();                 // cur buffer visible to all
        __builtin_amdgcn_sched_barrier(0);

        bf16x8 af[4], bfr[4];
        #pragma unroll
        for (int f = 0; f < 4; ++f) {
            af[f]  = *(const bf16x8*)&As[cur][(wm + f * 16 + l15) * 32 + l4 * 8];
            bfr[f] = *(const bf16x8*)&Bs[cur][(wn + f * 16 + l15) * 32 + l4 * 8];
        }
        asm volatile("s_waitcnt lgkmcnt(0)" ::: "memory");
        __builtin_amdgcn_sched_barrier(0);            // rule 18: pin reads complete
        __builtin_amdgcn_s_barrier();                 // all reads of cur done
        __builtin_amdgcn_sched_barrier(0);
        if (t + 2 < NIT) STAGEF(cur, (t + 2) * 32);   // overwrite cur for k=t+2

        #pragma unroll
        for (int i = 0; i < 4; ++i)
            #pragma unroll
            for (int j = 0; j < 4; ++j)
                acc[i][j] = __builtin_amdgcn_mfma_f32_16x16x32_bf16(af[i], bfr[j], acc[i][j], 0, 0, 0);
    }
    #undef STAGEF

    #pragma unroll
    for (int i = 0; i < 4; ++i) {
        const int n0 = wm + i * 16 + l4 * 4;
        #pragma unroll
        for (int j = 0; j < 4; ++j) {
            const int col = bn + wn + j * 16 + l15;
            float bsv = (col < 2 * HID) ? bias0[col] : bias1[col - 2 * HID];
            float vv[4];
            #pragma unroll
            for (int rr = 0; rr < 4; ++rr) {
                float v = acc[i][j][rr] + bsv;
                vv[rr] = v / (1.0f + __expf(-v));
            }
            if (col < HID) {
                ushort4 o = make_ushort4(f2bf(vv[0]), f2bf(vv[1]), f2bf(vv[2]), f2bf(vv[3]));
                *(ushort4*)&vTp[((size_t)byi * HID + col) * NIN + n0] = o;
            } else if (col < 2 * HID) {
                #pragma unroll
                for (int rr = 0; rr < 4; ++rr)
                    gatep[(size_t)(bm + n0 + rr) * HID + (col - HID)] = f2bf(vv[rr]);
            } else {
                #pragma unroll
                for (int rr = 0; rr < 4; ++rr)
                    Cf[(size_t)(bm + n0 + rr) * QKD + (col - 2 * HID)] = vv[rr];
            }
        }
    }
}

// ---------------- Wout GEMM: BM=256 x BN=128, BK=32, dbuf prefetch ----------------
__global__ __launch_bounds__(256, 2) void k_gemm_o(
        const unsigned short* __restrict__ A,
        const unsigned short* __restrict__ Bt,
        const float* __restrict__ bias0,
        const float* __restrict__ resid,
        float* __restrict__ Cf,
        int M, int N, int K) {
    __shared__ unsigned short As[2][256 * 32];
    __shared__ unsigned short Bs[2][128 * 32];
    const int tid = threadIdx.x;

    int flat = blockIdx.y * gridDim.x + blockIdx.x;
    int nwg  = gridDim.x * gridDim.y;
    int q = nwg >> 3, r = nwg & 7;
    int xcd = flat & 7, idx = flat >> 3;
    int swz = (xcd < r ? xcd * (q + 1) : r * (q + 1) + (xcd - r) * q) + idx;
    const int bxi = swz % gridDim.x, byi = swz / gridDim.x;
    const int bm = byi * 256, bn = bxi * 128;

    const int lane = tid & 63, wave = tid >> 6;   // wave w: rows [64w, 64w+64)
    const int l15 = lane & 15, l4 = lane >> 4;

    f32x4 acc[4][8];
    #pragma unroll
    for (int i = 0; i < 4; ++i)
        #pragma unroll
        for (int j = 0; j < 8; ++j) acc[i][j] = (f32x4){0.f, 0.f, 0.f, 0.f};

    const int rowA = tid >> 2;
    const int colO = (tid & 3) * 16;
    const int colS = colO ^ ((rowA & 3) << 4);
    const char* gA = (const char*)(A  + (size_t)(bm + rowA) * K) + colS;
    const char* gB = (const char*)(Bt + (size_t)(bn + rowA) * K) + colS;
    const size_t stride64 = (size_t)64 * K * 2;
    unsigned short* dA0 = &As[0][tid * 8];
    unsigned short* dA1 = &As[1][tid * 8];
    unsigned short* dB0 = &Bs[0][tid * 8];
    unsigned short* dB1 = &Bs[1][tid * 8];

    #define STAGE2(dA, dB, k0) do { \
        const char* sA_ = gA + (size_t)(k0) * 2; \
        const char* sB_ = gB + (size_t)(k0) * 2; \
        GLOAD_LDS(sA_,                 (dA)); \
        GLOAD_LDS(sA_ +     stride64,  (dA) + 2048); \
        GLOAD_LDS(sA_ + 2 * stride64,  (dA) + 4096); \
        GLOAD_LDS(sA_ + 3 * stride64,  (dA) + 6144); \
        GLOAD_LDS(sB_,                 (dB)); \
        GLOAD_LDS(sB_ +     stride64,  (dB) + 2048); \
    } while (0)

    STAGE2(dA0, dB0, 0);
    asm volatile("s_waitcnt vmcnt(0)" ::: "memory");
    __syncthreads();

    const int NIT = K / 32;
    int bufc = 0;
    for (int it = 0; it < NIT; ++it) {
        if (it + 1 < NIT) {
            if (bufc == 0) STAGE2(dA1, dB1, (it + 1) * 32);
            else           STAGE2(dA0, dB0, (it + 1) * 32);
        }
        const unsigned short* Ab = As[bufc];
        const unsigned short* Bb = Bs[bufc];
        bf16x8 af[4], bfr[8];
        #pragma unroll
        for (int f = 0; f < 4; ++f) {
            int rA = wave * 64 + f * 16 + l15;
            af[f] = *(const bf16x8*)&Ab[rA * 32 + ((l4 ^ (rA & 3)) << 3)];
        }
        #pragma unroll
        for (int c = 0; c < 8; ++c) {
            int rB = c * 16 + l15;
            bfr[c] = *(const bf16x8*)&Bb[rB * 32 + ((l4 ^ (rB & 3)) << 3)];
        }
        #pragma unroll
        for (int f = 0; f < 4; ++f)
            #pragma unroll
            for (int c = 0; c < 8; ++c)
                acc[f][c] = __builtin_amdgcn_mfma_f32_16x16x32_bf16(af[f], bfr[c], acc[f][c], 0, 0, 0);
        asm volatile("s_waitcnt vmcnt(0)" ::: "memory");
        __syncthreads();
        bufc ^= 1;
    }
    #undef STAGE2

    #pragma unroll
    for (int f = 0; f < 4; ++f) {
        const int n0 = wave * 64 + f * 16 + l4 * 4;
        #pragma unroll
        for (int c = 0; c < 8; ++c) {
            const int col = bn + c * 16 + l15;
            float bsv = bias0[col];
            #pragma unroll
            for (int rr = 0; rr < 4; ++rr) {
                size_t row = bm + n0 + rr;
                Cf[row * N + col] = acc[f][c][rr] + bsv + resid[row * N + col];
            }
        }
    }
}

// ---------------- rotary cos/sin tables ----------------
__global__ void k_cossin(float* __restrict__ cosb, float* __restrict__ sinb) {
    int idx = blockIdx.x * 256 + threadIdx.x;
    if (idx >= NIN * 16) return;
    int n = idx / 16, i = idx % 16;
    double inv = pow(10000.0, -(double)(2 * i) / (double)ROT);
    double f = (double)n * inv;
    cosb[idx] = (float)cos(f);
    sinb[idx] = (float)sin(f);
}

// ---------------- qs = qk*gamma+beta (4 heads) + rotary, bf16 out ----------------
__global__ void k_rot(const float* __restrict__ qk, const float* __restrict__ gm,
                      const float* __restrict__ bt, const float* __restrict__ cosb,
                      const float* __restrict__ sinb, unsigned short* __restrict__ q4) {
    int bn = blockIdx.x; int n = bn % NIN;
    int d = threadIdx.x;   // 128
    float x = qk[(size_t)bn * QKD + d];
    float xp0 = 0.f;
    int dp = d ^ 1;
    if (d < ROT) xp0 = qk[(size_t)bn * QKD + dp];
    #pragma unroll
    for (int c = 0; c < 4; ++c) {
        float val = x * gm[c * QKD + d] + bt[c * QKD + d];
        float outv;
        if (d < ROT) {
            int i = d >> 1;
            float cs = cosb[n * 16 + i], sn = sinb[n * 16 + i];
            float xp = xp0 * gm[c * QKD + dp] + bt[c * QKD + dp];
            outv = ((d & 1) == 0) ? (val * cs - xp * sn) : (val * cs + xp * sn);
        } else outv = val;
        q4[((size_t)bn * 4 + c) * QKD + d] = f2bf(outv);
    }
}

// ---------------- MFMA fused attention ----------------
__global__ __launch_bounds__(256) void k_attn2(
        const unsigned short* __restrict__ q4,
        const unsigned short* __restrict__ gatep,
        const unsigned short* __restrict__ vT,
        const float* __restrict__ rp,
        unsigned short* __restrict__ attn_out) {
    int et = blockIdx.x, b = blockIdx.y;
    int tid = threadIdx.x, wave = tid >> 6, lane = tid & 63;
    int l31 = lane & 31, lhi = lane >> 5;

    __shared__ unsigned short S[32][136];
    __shared__ float rps_d[32];
    if (tid < 32) {
        int d = tid, bucket;
        if (d < 16) bucket = d;
        else {
            bucket = 16 + (int)(logf((float)d * (1.0f / 16.0f)) * (16.0f / logf(8.0f)));
            if (bucket > 31) bucket = 31;
        }
        rps_d[tid] = rp[bucket] * sqrtf((float)QKD);
    }
    __syncthreads();

    size_t bbase = (size_t)b * NIN;
    int e0 = et * 256 + wave * 64;
    const unsigned short* vbase = vT + (size_t)b * HID * NIN;

    for (int g = 0; g < GRP; ++g) {
        if (wave <= g) {
            int gp = wave;
            bool quad = (gp == g);
            const unsigned short* Qb = q4 + ((bbase + g  * 32 + l31) * 4 + (quad ? 0 : 1)) * QKD;
            const unsigned short* Kb = q4 + ((bbase + gp * 32 + l31) * 4 + (quad ? 2 : 3)) * QKD;
            f32x16 sa = {};
            #pragma unroll
            for (int kk = 0; kk < 8; ++kk) {
                bf16x8 aq = *(const bf16x8*)(Qb + kk * 16 + lhi * 8);
                bf16x8 bk = *(const bf16x8*)(Kb + kk * 16 + lhi * 8);
                sa = __builtin_amdgcn_mfma_f32_32x32x16_bf16(aq, bk, sa, 0, 0, 0);
            }
            int j = l31;
            #pragma unroll
            for (int r = 0; r < 16; ++r) {
                int i = (r & 3) + 8 * (r >> 2) + 4 * lhi;
                float s = sa[r] * (1.0f / GSZ);
                if (quad) {
                    if (j > i) s = 0.f;
                    else {
                        s += rps_d[i - j];
                        s = fmaxf(s, 0.f);
                        s = s * s;
                    }
                }
                S[i][gp * 32 + j] = f2bf(s);
            }
        }
        __syncthreads();

        f32x16 o0 = {}, o1 = {};
        int KT = 2 * (g + 1);
        for (int kk = 0; kk < KT; ++kk) {
            int k0 = kk * 16 + lhi * 8;
            bf16x8 af = *(const bf16x8*)&S[l31][k0];
            bf16x8 b0 = *(const bf16x8*)(vbase + (size_t)(e0 + l31) * NIN + k0);
            bf16x8 b1 = *(const bf16x8*)(vbase + (size_t)(e0 + 32 + l31) * NIN + k0);
            o0 = __builtin_amdgcn_mfma_f32_32x32x16_bf16(af, b0, o0, 0, 0, 0);
            o1 = __builtin_amdgcn_mfma_f32_32x32x16_bf16(af, b1, o1, 0, 0, 0);
        }
        __syncthreads();

        int ea = e0 + l31, eb = e0 + 32 + l31;
        #pragma unroll
        for (int r = 0; r < 16; ++r) {
            int i = (r & 3) + 8 * (r >> 2) + 4 * lhi;
            size_t row = bbase + g * 32 + i;
            float ga = bf2f(gatep[row * HID + ea]);
            float gb = bf2f(gatep[row * HID + eb]);
            attn_out[row * HID + ea] = f2bf(ga * o0[r]);
            attn_out[row * HID + eb] = f2bf(gb * o1[r]);
        }
    }
}

// ---------------- final LayerNorm ----------------
__global__ void k_ln(const float* __restrict__ h, const float* __restrict__ lng,
                     const float* __restrict__ lnb, float* __restrict__ out) {
    int bn = blockIdx.x;
    int t = threadIdx.x;
    const float4* r4 = (const float4*)(h + (size_t)bn * DIMD);
    float4 v = r4[t];
    float s  = v.x + v.y + v.z + v.w;
    float sq = v.x * v.x + v.y * v.y + v.z * v.z + v.w * v.w;
    __shared__ float red[4];
    #pragma unroll
    for (int o = 32; o; o >>= 1) { s += __shfl_down(s, o); sq += __shfl_down(sq, o); }
    int lane = t & 63, w = t >> 6;
    if (lane == 0) { red[w] = s; red[2 + w] = sq; }
    __syncthreads();
    float mu  = (red[0] + red[1]) * (1.0f / DIMD);
    float var = (red[2] + red[3]) * (1.0f / DIMD) - mu * mu;
    float rstd = 1.0f / sqrtf(var + EPSF);
    float4 gg = ((const float4*)lng)[t];
    float4 bb = ((const float4*)lnb)[t];
    float4 o;
    o.x = (v.x - mu) * rstd * gg.x + bb.x;
    o.y = (v.y - mu) * rstd * gg.y + bb.y;
    o.z = (v.z - mu) * rstd * gg.z + bb.z;
    o.w = (v.w - mu) * rstd * gg.w + bb.w;
    ((float4*)(out + (size_t)bn * DIMD))[t] = o;
}

extern "C" void kernel_launch(void* const* d_in, const int* in_sizes, int n_in,
                              void* d_out, int out_size, void* d_ws, size_t ws_size,
                              hipStream_t stream) {
    const int*   tokens = (const int*)d_in[0];
    const float* emb    = (const float*)d_in[1];
    const float* pos    = (const float*)d_in[2];
    const float* norm_g = (const float*)d_in[3];
    const float* Wh     = (const float*)d_in[4];
    const float* bh     = (const float*)d_in[5];
    const float* Wqk    = (const float*)d_in[6];
    const float* bqk    = (const float*)d_in[7];
    const float* gamma  = (const float*)d_in[8];
    const float* beta   = (const float*)d_in[9];
    const float* rp     = (const float*)d_in[10];
    const float* Wout   = (const float*)d_in[11];
    const float* bout   = (const float*)d_in[12];
    const float* lng    = (const float*)d_in[13];
    const float* lnb    = (const float*)d_in[14];

    float* h  = (float*)d_out;
    float* ws = (float*)d_ws;

    // ---- fixed allocations ----
    size_t off = 0;
    float* cosb  = ws + off; off += NIN * 16;
    float* sinb  = ws + off; off += NIN * 16;
    unsigned short* whqkT = (unsigned short*)(ws + off); off += (size_t)NLAYER * NFUSE * DIMD / 2;
    unsigned short* woutT = (unsigned short*)(ws + off); off += (size_t)NLAYER * DIMD * HID / 2;
    off = (off + 63) & ~(size_t)63;
    const size_t fixedFloats = off;

    // ---- size batch chunk (keep CB >= 2 so M % 256 == 0 for k_gemm_o) ----
    const size_t wsFloats = ws_size / sizeof(float);
    const size_t perBatch = (size_t)NIN * (DIMD / 2 + HID / 2 + HID / 2 + QKD + DIMD / 2 + HID / 2);
    int CB = BB;
    while (CB > 2 && fixedFloats + (size_t)CB * perBatch + 64 > wsFloats) CB >>= 1;

    unsigned short* nx    = (unsigned short*)(ws + off); off += (size_t)CB * NIN * DIMD / 2;
    unsigned short* vT    = (unsigned short*)(ws + off); off += (size_t)CB * HID * NIN / 2;
    unsigned short* gateB = (unsigned short*)(ws + off); off += (size_t)CB * NIN * HID / 2;
    float*          qk    = ws + off;                    off += (size_t)CB * NIN * QKD;
    unsigned short* q4    = (unsigned short*)(ws + off); off += (size_t)CB * NIN * DIMD / 2;
    unsigned short* attnB = (unsigned short*)(ws + off); off += (size_t)CB * NIN * HID / 2;

    const int BN_ = BB * NIN;

    k_cossin<<<8, 256, 0, stream>>>(cosb, sinb);
    k_embed<<<BN_, 128, 0, stream>>>(tokens, emb, pos, h);

    for (int l = 0; l < NLAYER; ++l) {
        unsigned short* whqkT_l = whqkT + (size_t)l * NFUSE * DIMD;
        k_wcast<<<(HID2 * DIMD / 8 + 255) / 256, 256, 0, stream>>>(
            Wh + (size_t)l * DIMD * HID2,  whqkT_l, DIMD, HID2);
        k_wcast<<<(QKD * DIMD / 8 + 255) / 256, 256, 0, stream>>>(
            Wqk + (size_t)l * DIMD * QKD,  whqkT_l + (size_t)HID2 * DIMD, DIMD, QKD);
        k_wcast<<<(DIMD * HID / 8 + 255) / 256, 256, 0, stream>>>(
            Wout + (size_t)l * HID * DIMD, woutT + (size_t)l * DIMD * HID, HID, DIMD);
    }

    for (int l = 0; l < NLAYER; ++l) {
        const float* bh_l  = bh   + (size_t)l * HID2;
        const float* bqk_l = bqk  + (size_t)l * QKD;
        const float* gm_l  = gamma+ (size_t)l * 4 * QKD;
        const float* bt_l  = beta + (size_t)l * 4 * QKD;
        const float* rp_l  = rp   + (size_t)l * 32;
        const float* bo_l  = bout + (size_t)l * DIMD;
        const unsigned short* whqkT_l = whqkT + (size_t)l * NFUSE * DIMD;
        const unsigned short* woutT_l = woutT + (size_t)l * DIMD * HID;

        for (int c0 = 0; c0 < BB; c0 += CB) {
            const int rowsC = CB * NIN;
            float* h_c = h + (size_t)c0 * NIN * DIMD;

            k_nxf<<<rowsC, 128, 0, stream>>>(h_c, nx, norm_g + l);

            dim3 g1(NFUSE / 128, rowsC / 128);
            k_gemm_f<<<g1, 256, 0, stream>>>(nx, whqkT_l, bh_l, bqk_l,
                                             qk, vT, gateB, rowsC, NFUSE, DIMD);

            k_rot<<<rowsC, 128, 0, stream>>>(qk, gm_l, bt_l, cosb, sinb, q4);

            dim3 ga(HID / 256, CB);
            k_attn2<<<ga, 256, 0, stream>>>(q4, gateB, vT, rp_l, attnB);

            dim3 g3(DIMD / 128, rowsC / 256);
            k_gemm_o<<<g3, 256, 0, stream>>>(attnB, woutT_l, bo_l, h_c, h_c,
                                             rowsC, DIMD, HID);
        }
    }

    k_ln<<<BN_, 128, 0, stream>>>(h, lng, lnb, (float*)d_out);
}